// Round 1
// 490.407 us; speedup vs baseline: 1.3836x; 1.3836x over previous
//
#include <hip/hip_runtime.h>
#include <math.h>

// Problem constants
#define BB   2
#define LL   1024
#define HH   768
#define NHH  12
#define NEE  24
#define MMM  3
#define NCC  2
#define CWW  8
#define BLK  64
#define NCLS 97
#define KB   12          // HH/BLK
#define HB   49152       // HH*BLK
#define NCP  128         // padded class dim for Wf
#define NCT  7           // class tiles computed (112 >= 97)
#define NEF  1152        // BB*NEE*NEE

typedef unsigned int uint;
typedef unsigned short ushort;
typedef __attribute__((ext_vector_type(8))) short bf16x8;
typedef __attribute__((ext_vector_type(4))) float f32x4;

// round-to-nearest-even fp32 -> bf16
__device__ __forceinline__ ushort f2bf(float f) {
    uint u = __float_as_uint(f);
    u += 0x7fffu + ((u >> 16) & 1u);
    return (ushort)(u >> 16);
}

// ---------------------------------------------------------------------------
// K1: e_att[b,e,h,l] = mean_m attention[b,h,ms[b,e,m]+1,l]
__global__ void k_eatt(const float* __restrict__ att_in, const int* __restrict__ ms,
                       float* __restrict__ e_att) {
    int blk = blockIdx.x;               // (b*NEE+e)*NHH + h
    int h = blk % NHH;
    int e = (blk / NHH) % NEE;
    int b = blk / (NHH * NEE);
    int base = (b * NEE + e) * MMM;
    int p0 = ms[base + 0] + 1;
    int p1 = ms[base + 1] + 1;
    int p2 = ms[base + 2] + 1;
    const float* r0 = att_in + ((size_t)(b * NHH + h) * LL + p0) * LL;
    const float* r1 = att_in + ((size_t)(b * NHH + h) * LL + p1) * LL;
    const float* r2 = att_in + ((size_t)(b * NHH + h) * LL + p2) * LL;
    float* o = e_att + ((size_t)(b * NEE + e) * NHH + h) * LL;
    for (int l = threadIdx.x; l < LL; l += blockDim.x)
        o[l] = (r0[l] + r1[l] + r2[l]) * (1.f / 3.f);
}

// K2: gate[b,e,l] = att[l]/sum_l att[l], att[l]=sum_h e_att
__global__ void k_gate(const float* __restrict__ e_att, float* __restrict__ gate) {
    int be = blockIdx.x;
    __shared__ float att_s[LL];
    __shared__ float red[4];
    const float* ea = e_att + (size_t)be * NHH * LL;
    float lsum = 0.f;
    for (int l = threadIdx.x; l < LL; l += blockDim.x) {
        float a = 0.f;
        for (int h = 0; h < NHH; h++) a += ea[h * LL + l];
        att_s[l] = a;
        lsum += a;
    }
    for (int off = 32; off; off >>= 1) lsum += __shfl_down(lsum, off, 64);
    if ((threadIdx.x & 63) == 0) red[threadIdx.x >> 6] = lsum;
    __syncthreads();
    float inv = 1.f / (red[0] + red[1] + red[2] + red[3]);
    for (int l = threadIdx.x; l < LL; l += blockDim.x)
        gate[(size_t)be * LL + l] = att_s[l] * inv;
}

// K3: e_emb[b,e,d] = logsumexp over {3 mention embeds, 2 coref embeds}
__global__ void k_eemb(const float* __restrict__ seq, const float* __restrict__ gate,
                       const int* __restrict__ ms, const int* __restrict__ cs,
                       float* __restrict__ e_emb) {
    int be = blockIdx.x;
    int b = be / NEE;
    int p0 = ms[be * MMM + 0] + 1, p1 = ms[be * MMM + 1] + 1, p2 = ms[be * MMM + 2] + 1;
    int c0 = cs[be * NCC + 0], c1 = cs[be * NCC + 1];
    for (int d = threadIdx.x; d < HH; d += blockDim.x) {
        float v0 = seq[((size_t)b * LL + p0) * HH + d];
        float v1 = seq[((size_t)b * LL + p1) * HH + d];
        float v2 = seq[((size_t)b * LL + p2) * HH + d];
        float s0 = 0.f, s1 = 0.f;
        for (int w = 0; w < CWW; w++) {
            s0 += gate[(size_t)be * LL + c0 + w] * seq[((size_t)b * LL + c0 + w) * HH + d];
            s1 += gate[(size_t)be * LL + c1 + w] * seq[((size_t)b * LL + c1 + w) * HH + d];
        }
        float mx = fmaxf(fmaxf(fmaxf(v0, v1), fmaxf(v2, s0)), s1);
        float s = expf(v0 - mx) + expf(v1 - mx) + expf(v2 - mx) + expf(s0 - mx) + expf(s1 - mx);
        e_emb[(size_t)be * HH + d] = logf(s) + mx;
    }
}

// K4: ht[b,e,f,l] = relu(sum_h e_att[b,e,h,l]*e_att[b,f,h,l]) normalized over l
__global__ void k_ht(const float* __restrict__ e_att, float* __restrict__ ht) {
    int blk = blockIdx.x;   // ((b*NEE+e)*NEE+f)
    int f = blk % NEE;
    int e = (blk / NEE) % NEE;
    int b = blk / (NEE * NEE);
    const float* ea = e_att + (size_t)(b * NEE + e) * NHH * LL;
    const float* fa = e_att + (size_t)(b * NEE + f) * NHH * LL;
    __shared__ float hts[LL];
    __shared__ float red[4];
    float lsum = 0.f;
    for (int l = threadIdx.x; l < LL; l += blockDim.x) {
        float s = 0.f;
        for (int h = 0; h < NHH; h++) s += ea[h * LL + l] * fa[h * LL + l];
        s = fmaxf(s, 0.f);
        hts[l] = s;
        lsum += s;
    }
    for (int off = 32; off; off >>= 1) lsum += __shfl_down(lsum, off, 64);
    if ((threadIdx.x & 63) == 0) red[threadIdx.x >> 6] = lsum;
    __syncthreads();
    float inv = 1.f / (red[0] + red[1] + red[2] + red[3] + 1e-10f);
    for (int l = threadIdx.x; l < LL; l += blockDim.x)
        ht[(size_t)blk * LL + l] = hts[l] * inv;
}

// K5a: zero rs ahead of atomic accumulation
__global__ void k_zrs(float* __restrict__ rs) {
    int i = blockIdx.x * 256 + threadIdx.x;
    rs[i] = 0.f;
}

// K5: rs[b,(e,f),d] = sum_l ht[b,(e,f),l]*seq[b,l,d].
// Per batch b: C(576x768) = A(576x1024) @ B(1024x768), fp32.
// 64x64 output tiles, 4x4 per thread (k_rsw-proven structure), K split in two
// 512-halves via blockIdx.z for grid 432 (was 144 -> latency-bound at 6.6%
// occupancy, VALUBusy 12%). fp32 atomicAdd into zero-inited rs (2 writers per
// address).
__global__ void k_rs(const float* __restrict__ seq, const float* __restrict__ ht,
                     float* __restrict__ rs) {
    int m0 = blockIdx.x * 64;           // 0..576
    int n0 = blockIdx.y * 64;           // 0..768
    int b  = blockIdx.z >> 1;
    int k0base = (blockIdx.z & 1) * 512;
    const float* A  = ht  + (size_t)b * 576 * 1024;
    const float* Bm = seq + (size_t)b * 1024 * 768;
    float* C = rs + (size_t)b * 576 * 768;
    __shared__ float As[16][68], Bs[16][68];
    int tx = threadIdx.x & 15, ty = threadIdx.x >> 4;
    int lr = threadIdx.x >> 2;          // 0..63  (A row within tile)
    int lk = (threadIdx.x & 3) * 4;     // 0,4,8,12 (A k within step)
    int kr = threadIdx.x >> 4;          // 0..15  (B row within step)
    int c4 = (threadIdx.x & 15) * 4;    // B col (float4)
    float acc[4][4] = {};
    const float* arow = A + (size_t)(m0 + lr) * 1024 + k0base;
    const float* brow = Bm + (size_t)(k0base + kr) * 768 + n0 + c4;
    for (int k0 = 0; k0 < 512; k0 += 16) {
        float4 av = *(const float4*)(arow + k0 + lk);
        float4 bv = *(const float4*)(brow + (size_t)k0 * 768);
        __syncthreads();
        As[lk + 0][lr] = av.x; As[lk + 1][lr] = av.y; As[lk + 2][lr] = av.z; As[lk + 3][lr] = av.w;
        *(float4*)&Bs[kr][c4] = bv;
        __syncthreads();
#pragma unroll
        for (int kk = 0; kk < 16; kk++) {
            float a0 = As[kk][ty * 4 + 0], a1 = As[kk][ty * 4 + 1];
            float a2 = As[kk][ty * 4 + 2], a3 = As[kk][ty * 4 + 3];
            float b0 = Bs[kk][tx * 4 + 0], b1 = Bs[kk][tx * 4 + 1];
            float b2 = Bs[kk][tx * 4 + 2], b3 = Bs[kk][tx * 4 + 3];
            acc[0][0] += a0 * b0; acc[0][1] += a0 * b1; acc[0][2] += a0 * b2; acc[0][3] += a0 * b3;
            acc[1][0] += a1 * b0; acc[1][1] += a1 * b1; acc[1][2] += a1 * b2; acc[1][3] += a1 * b3;
            acc[2][0] += a2 * b0; acc[2][1] += a2 * b1; acc[2][2] += a2 * b2; acc[2][3] += a2 * b3;
            acc[3][0] += a3 * b0; acc[3][1] += a3 * b1; acc[3][2] += a3 * b2; acc[3][3] += a3 * b3;
        }
    }
#pragma unroll
    for (int i = 0; i < 4; i++)
#pragma unroll
        for (int j = 0; j < 4; j++)
            atomicAdd(&C[(size_t)(m0 + ty * 4 + i) * 768 + n0 + tx * 4 + j], acc[i][j]);
}

// K6a: hsW[m2,d] = sum_j e_emb[m2,j]*Wm[d,j] (first HH cols of Wh/Wt).
__global__ void k_hw(const float* __restrict__ e_emb, const float* __restrict__ Wh,
                     const float* __restrict__ Wt, float* __restrict__ hsW,
                     float* __restrict__ tsW) {
    int m2 = blockIdx.x;          // 0..47
    int which = blockIdx.y;       // 0..1
    int chunk = blockIdx.z;       // 0..11 (64 d's each)
    const float* Wm = which ? Wt : Wh;
    float* outp = which ? tsW : hsW;
    __shared__ float xs[HH];
    const float* x = e_emb + (size_t)m2 * HH;
    for (int j = threadIdx.x; j < HH; j += 256) xs[j] = x[j];
    __syncthreads();
    int lane = threadIdx.x & 63, w = threadIdx.x >> 6;
    int d0 = chunk * 64 + w * 16;
#pragma unroll 4
    for (int i = 0; i < 16; i++) {
        int d = d0 + i;
        const float* wr = Wm + (size_t)d * (2 * HH);
        float s = 0.f;
#pragma unroll
        for (int jj = 0; jj < 12; jj++) s += xs[lane + jj * 64] * wr[lane + jj * 64];
        for (int off = 32; off; off >>= 1) s += __shfl_down(s, off, 64);
        if (lane == 0) outp[(size_t)m2 * HH + d] = s;
    }
}

// K6b: rsW[m,n] = sum_k rs[m,k] * W2[n,k], W2 = [W_head[:,768:]; W_tail[:,768:]]
__global__ void k_rsw(const float* __restrict__ rs, const float* __restrict__ Wh,
                      const float* __restrict__ Wt, float* __restrict__ rsW) {
    int m0 = blockIdx.x * 64, n0 = blockIdx.y * 64;
    __shared__ float As[16][68], Bs[16][68];
    int tx = threadIdx.x & 15, ty = threadIdx.x >> 4;
    int lr = threadIdx.x >> 2;          // 0..63
    int lk = (threadIdx.x & 3) * 4;     // 0,4,8,12
    float acc[4][4] = {};
    int n = n0 + lr;
    const float* brow = (n < HH) ? (Wh + (size_t)n * (2 * HH) + HH)
                                 : (Wt + (size_t)(n - HH) * (2 * HH) + HH);
    const float* arow = rs + (size_t)(m0 + lr) * HH;
    for (int k0 = 0; k0 < HH; k0 += 16) {
        float4 av = *(const float4*)(arow + k0 + lk);
        float4 bv = *(const float4*)(brow + k0 + lk);
        __syncthreads();
        As[lk + 0][lr] = av.x; As[lk + 1][lr] = av.y; As[lk + 2][lr] = av.z; As[lk + 3][lr] = av.w;
        Bs[lk + 0][lr] = bv.x; Bs[lk + 1][lr] = bv.y; Bs[lk + 2][lr] = bv.z; Bs[lk + 3][lr] = bv.w;
        __syncthreads();
#pragma unroll
        for (int kk = 0; kk < 16; kk++) {
            float a0 = As[kk][ty * 4 + 0], a1 = As[kk][ty * 4 + 1];
            float a2 = As[kk][ty * 4 + 2], a3 = As[kk][ty * 4 + 3];
            float b0 = Bs[kk][tx * 4 + 0], b1 = Bs[kk][tx * 4 + 1];
            float b2 = Bs[kk][tx * 4 + 2], b3 = Bs[kk][tx * 4 + 3];
            acc[0][0] += a0 * b0; acc[0][1] += a0 * b1; acc[0][2] += a0 * b2; acc[0][3] += a0 * b3;
            acc[1][0] += a1 * b0; acc[1][1] += a1 * b1; acc[1][2] += a1 * b2; acc[1][3] += a1 * b3;
            acc[2][0] += a2 * b0; acc[2][1] += a2 * b1; acc[2][2] += a2 * b2; acc[2][3] += a2 * b3;
            acc[3][0] += a3 * b0; acc[3][1] += a3 * b1; acc[3][2] += a3 * b2; acc[3][3] += a3 * b3;
        }
    }
#pragma unroll
    for (int i = 0; i < 4; i++)
#pragma unroll
        for (int j = 0; j < 4; j++)
            rsW[(size_t)(m0 + ty * 4 + i) * (2 * HH) + n0 + tx * 4 + j] = acc[i][j];
}

// K7: zb = bf16(tanh(rsW + hsW/tsW + bias)).  hs uses e_emb[b,e], ts uses e_emb[b,f]
__global__ void k_tanh(const float* __restrict__ rsW, const float* __restrict__ hsW,
                       const float* __restrict__ tsW, const float* __restrict__ bh,
                       const float* __restrict__ bt, ushort* __restrict__ zb) {
    size_t i = (size_t)blockIdx.x * 256 + threadIdx.x;
    if (i >= (size_t)NEF * 2 * HH) return;
    int nn = (int)(i % (2 * HH));
    int m = (int)(i / (2 * HH));
    int f = m % NEE;
    int e = (m / NEE) % NEE;
    int b = m / (NEE * NEE);
    float v = rsW[i];
    if (nn < HH) v = tanhf(v + hsW[(size_t)(b * NEE + e) * HH + nn] + bh[nn]);
    else {
        int d = nn - HH;
        v = tanhf(v + tsW[(size_t)(b * NEE + f) * HH + d] + bt[d]);
    }
    zb[i] = f2bf(v);
}

// K8a: pre-pack W_cls into bf16 MFMA-B-fragment order (one uint4 per thread):
// wcpack[((kc*NCT + ct)*64 + lane)*8 + j] = bf16(Wc[(ct*16 + (lane&15))*HH +
//                                                    kc*32 + (lane>>4)*8 + j]), 0 if c>=NCLS
__global__ void k_wcp(const float* __restrict__ Wc, ushort* __restrict__ wcpack) {
    int t = blockIdx.x * 256 + threadIdx.x;
    if (t >= 24 * NCT * 64) return;
    int kc = t / (NCT * 64);
    int r = t % (NCT * 64);
    int ct = r >> 6;
    int lane = r & 63;
    int c = ct * 16 + (lane & 15);
    int k0 = kc * 32 + (lane >> 4) * 8;
    uint u[4] = {0u, 0u, 0u, 0u};
    if (c < NCLS) {
        const float* src = Wc + (size_t)c * HH + k0;
        float4 f0 = *(const float4*)src;
        float4 f1 = *(const float4*)(src + 4);
        u[0] = (uint)f2bf(f0.x) | ((uint)f2bf(f0.y) << 16);
        u[1] = (uint)f2bf(f0.z) | ((uint)f2bf(f0.w) << 16);
        u[2] = (uint)f2bf(f1.x) | ((uint)f2bf(f1.y) << 16);
        u[3] = (uint)f2bf(f1.z) | ((uint)f2bf(f1.w) << 16);
    }
    *(uint4*)(wcpack + (size_t)t * 8) = make_uint4(u[0], u[1], u[2], u[3]);
}

// K8: bf16 MFMA GEMM for Wf: D[n, c] = sum_k Wp[k*HB + n] * Wc[c*HH + k].
// Barrier-free: A-fragments direct from global (8 dword loads, 4x64B segments,
// streams W_proj exactly once = 147 MB -> ~23 us HBM floor), B-fragments are
// single uint4 loads from L2-resident wcpack. Layout conventions identical to
// the verified k_logits (A: m=lane&15,k=tt*8+j; C/D: col=lane&15,row=tt*4+r).
// Grid 768 blocks x 4 waves (64 n per block, 16 n per wave), ~12 waves/CU.
__global__ void k_wf(const float* __restrict__ Wp, const ushort* __restrict__ wcpack,
                     ushort* __restrict__ bpack) {
    int tid = threadIdx.x;
    int lane = tid & 63, w = tid >> 6;
    int r16 = lane & 15, tt = lane >> 4;
    int n0 = blockIdx.x * 64 + w * 16;        // this wave's 16-n tile
    // A source: lane reads col n0+r16, rows tt*8 + j (j=0..7), per k-chunk
    const float* ap = Wp + (size_t)(tt * 8) * HB + n0 + r16;
    const uint4* wb = (const uint4*)wcpack;

    f32x4 acc[NCT];
    f32x4 zero = {0.f, 0.f, 0.f, 0.f};
#pragma unroll
    for (int ct = 0; ct < NCT; ct++) acc[ct] = zero;

    for (int kc = 0; kc < 24; kc++) {
        const float* a0 = ap + (size_t)(kc * 32) * HB;
        float f[8];
#pragma unroll
        for (int j = 0; j < 8; j++) f[j] = a0[(size_t)j * HB];
        union { bf16x8 v; uint u[4]; } a;
#pragma unroll
        for (int q = 0; q < 4; q++)
            a.u[q] = (__float_as_uint(f[2 * q]) >> 16) |
                     (__float_as_uint(f[2 * q + 1]) & 0xFFFF0000u);  // truncate pair
#pragma unroll
        for (int ct = 0; ct < NCT; ct++) {
            union { uint4 q; bf16x8 v; } b;
            b.q = wb[(size_t)(kc * NCT + ct) * 64 + lane];
            acc[ct] = __builtin_amdgcn_mfma_f32_16x16x32_bf16(a.v, b.v, acc[ct], 0, 0, 0);
        }
    }
    // store: n = n0 + tt*4 + r (C/D row), c = ct*16 + r16 (C/D col)
#pragma unroll
    for (int ct = 0; ct < NCT; ct++) {
        int c = ct * 16 + r16;
#pragma unroll
        for (int r = 0; r < 4; r++) {
            int n = n0 + tt * 4 + r;
            bpack[((size_t)(n >> 3) * NCP + c) * 8 + (n & 7)] = f2bf(acc[ct][r]);
        }
    }
}

// K9a: out init with b_cls
__global__ void k_init(float* __restrict__ out, const float* __restrict__ bc) {
    int i = blockIdx.x * 256 + threadIdx.x;
    if (i < NEF * NCLS) out[i] = bc[i % NCLS];
}

// K9: MFMA logits. out[m,c] += sum over K-slice of bl[m,k]*Wf[c,k],
// bl generated on the fly in A-fragment layout from zh/zt LDS tiles.
// Grid (NEF/64, 24): M-tile 64, K-slice 2048, fp32 atomic accumulation.
#define ZTP 88
#define ZHP 48
__global__ __launch_bounds__(256, 2) void k_logits(const ushort* __restrict__ zb,
                                                   const ushort* __restrict__ bpack,
                                                   float* __restrict__ out) {
    __shared__ ushort zhs[64 * ZHP];
    __shared__ ushort zts[64 * ZTP];
    __shared__ ushort Bls[16384];   // 32 KB: one K=128 stage of B-fragments
    int m0 = blockIdx.x * 64;
    int kb = blockIdx.y;            // K-slice of 2048
    int kg = kb >> 1;               // which 4096-block (i*64+j space)
    int ihalf = (kb & 1) * 32;      // which half of the i range
    int tid = threadIdx.x;
    int lane = tid & 63, w = tid >> 6;
    int tt = lane >> 4, r16 = lane & 15;
    int wm = (w & 1) * 32, wn = (w >> 1) * 64;

    // zt tile: 64 rows x 64 cols (cols kg*64..+64 of the zt half)
    {
        int row = tid >> 2, c8 = (tid & 3) * 16;
        const ushort* src = zb + (size_t)(m0 + row) * 1536 + 768 + kg * 64 + c8;
        uint4 v0 = *(const uint4*)src;
        uint4 v1 = *(const uint4*)(src + 8);
        *(uint4*)&zts[row * ZTP + c8] = v0;
        *(uint4*)&zts[row * ZTP + c8 + 8] = v1;
    }
    // zh tile: 64 rows x 32 cols (cols kg*64+ihalf..+32 of the zh half)
    {
        int row = tid >> 2, c8 = (tid & 3) * 8;
        const ushort* src = zb + (size_t)(m0 + row) * 1536 + kg * 64 + ihalf + c8;
        *(uint4*)&zhs[row * ZHP + c8] = *(const uint4*)src;
    }

    f32x4 acc[2][4];
    f32x4 zero = {0.f, 0.f, 0.f, 0.f};
#pragma unroll
    for (int t = 0; t < 2; t++)
#pragma unroll
        for (int n = 0; n < 4; n++) acc[t][n] = zero;

    const char* bbase = (const char*)bpack + (size_t)kb * 2048 * 256;
    for (int g = 0; g < 16; g++) {
        __syncthreads();
        const char* sb = bbase + (size_t)g * 32768;
#pragma unroll
        for (int q = 0; q < 8; q++) {
            int off = (q * 4 + w) * 1024;
            __builtin_amdgcn_global_load_lds(
                (const __attribute__((address_space(1))) void*)(sb + off + lane * 16),
                (__attribute__((address_space(3))) void*)((char*)Bls + off),
                16, 0, 0);
        }
        __syncthreads();
#pragma unroll
        for (int ks = 0; ks < 4; ks++) {
            int s = g * 4 + ks;
            int il = s >> 1;            // i within this slice's half
            int j0 = (s & 1) * 32;      // j chunk base
            bf16x8 af[2];
#pragma unroll
            for (int t = 0; t < 2; t++) {
                int row = wm + t * 16 + r16;
                float zhf = __uint_as_float((uint)zhs[row * ZHP + il] << 16);
                union { bf16x8 v; uint u[4]; } zt8, a;
                zt8.v = *(const bf16x8*)&zts[row * ZTP + j0 + tt * 8];
#pragma unroll
                for (int q = 0; q < 4; q++) {
                    uint p = zt8.u[q];
                    uint lo = __float_as_uint(__uint_as_float(p << 16) * zhf);
                    uint hi = __float_as_uint(__uint_as_float(p & 0xFFFF0000u) * zhf);
                    a.u[q] = (lo >> 16) | (hi & 0xFFFF0000u);   // truncate-to-bf16 pair
                }
                af[t] = a.v;
            }
#pragma unroll
            for (int n = 0; n < 4; n++) {
                bf16x8 bf = *(const bf16x8*)&Bls[(size_t)((ks * 4 + tt) * NCP + wn + n * 16 + r16) * 8];
                acc[0][n] = __builtin_amdgcn_mfma_f32_16x16x32_bf16(af[0], bf, acc[0][n], 0, 0, 0);
                acc[1][n] = __builtin_amdgcn_mfma_f32_16x16x32_bf16(af[1], bf, acc[1][n], 0, 0, 0);
            }
        }
    }
    // epilogue: C/D layout col=lane&15, row=(lane>>4)*4+reg   [m89-verified]
    int rbase = (lane >> 4) * 4;
#pragma unroll
    for (int t = 0; t < 2; t++)
#pragma unroll
        for (int n = 0; n < 4; n++) {
            int c = wn + n * 16 + r16;
            if (c < NCLS) {
                int row = m0 + wm + t * 16 + rbase;
#pragma unroll
                for (int r = 0; r < 4; r++)
                    atomicAdd(&out[(size_t)(row + r) * NCLS + c], acc[t][n][r]);
            }
        }
}

// ---------------------------------------------------------------------------
extern "C" void kernel_launch(void* const* d_in, const int* in_sizes, int n_in,
                              void* d_out, int out_size, void* d_ws, size_t ws_size,
                              hipStream_t stream) {
    const float* seq  = (const float*)d_in[0];
    const float* attn = (const float*)d_in[1];
    const int*   ms   = (const int*)d_in[2];
    const int*   cs   = (const int*)d_in[3];
    const float* Wh   = (const float*)d_in[4];
    const float* bh   = (const float*)d_in[5];
    const float* Wt   = (const float*)d_in[6];
    const float* bt   = (const float*)d_in[7];
    const float* Wp   = (const float*)d_in[8];
    const float* Wc   = (const float*)d_in[9];
    const float* bc   = (const float*)d_in[10];
    float* out = (float*)d_out;

    // Workspace (floats). Region B is reused: gather scratch dies after k_tanh,
    // then bpack (bf16 Wf) overlays it. zb and wcpack sit past both live ranges.
    float* w     = (float*)d_ws;
    float* rsW   = w;                        // 1,769,472
    float* regB  = w + 1769472;
    float* e_att = regB;                     // 589,824
    float* gate  = e_att + 589824;           // 49,152
    float* ht    = gate + 49152;             // 1,179,648
    float* rs    = ht + 1179648;             // 884,736
    float* eemb  = rs + 884736;              // 36,864
    float* hsW   = eemb + 36864;             // 36,864
    float* tsW   = hsW + 36864;              // 36,864  (regB scratch ends at +2,813,952)
    ushort* bpack  = (ushort*)regB;            // 6,291,456 bf16 (overlays scratch, written after k_tanh)
    ushort* zb     = (ushort*)(regB + 3145728); // 1,769,472 bf16
    ushort* wcpack = (ushort*)(regB + 4030464); // 86,016 bf16 (W_cls B-fragments)

    k_wcp<<<(24 * NCT * 64 + 255) / 256, 256, 0, stream>>>(Wc, wcpack);
    k_eatt<<<BB * NEE * NHH, 256, 0, stream>>>(attn, ms, e_att);
    k_gate<<<BB * NEE, 256, 0, stream>>>(e_att, gate);
    k_eemb<<<BB * NEE, 256, 0, stream>>>(seq, gate, ms, cs, eemb);
    k_ht<<<NEF, 256, 0, stream>>>(e_att, ht);
    k_zrs<<<(NEF * HH) / 256, 256, 0, stream>>>(rs);
    k_rs<<<dim3(576 / 64, HH / 64, BB * 2), 256, 0, stream>>>(seq, ht, rs);
    k_hw<<<dim3(48, 2, 12), 256, 0, stream>>>(eemb, Wh, Wt, hsW, tsW);
    k_rsw<<<dim3(NEF / 64, 2 * HH / 64), 256, 0, stream>>>(rs, Wh, Wt, rsW);
    k_tanh<<<(NEF * 2 * HH + 255) / 256, 256, 0, stream>>>(rsW, hsW, tsW, bh, bt, zb);
    k_wf<<<HB / 64, 256, 0, stream>>>(Wp, wcpack, bpack);  // after k_tanh: clobbers scratch region
    k_init<<<(NEF * NCLS + 255) / 256, 256, 0, stream>>>(out, bc);
    k_logits<<<dim3(NEF / 64, 24), 256, 0, stream>>>(zb, bpack, out);
}

// Round 2
// 461.438 us; speedup vs baseline: 1.4705x; 1.0628x over previous
//
#include <hip/hip_runtime.h>
#include <math.h>

// Problem constants
#define BB   2
#define LL   1024
#define HH   768
#define NHH  12
#define NEE  24
#define MMM  3
#define NCC  2
#define CWW  8
#define BLK  64
#define NCLS 97
#define KB   12          // HH/BLK
#define HB   49152       // HH*BLK
#define NCP  128         // padded class dim for Wf
#define NCT  7           // class tiles computed (112 >= 97)
#define NEF  1152        // BB*NEE*NEE

typedef unsigned int uint;
typedef unsigned short ushort;
typedef __attribute__((ext_vector_type(8))) short bf16x8;
typedef __attribute__((ext_vector_type(4))) float f32x4;

// round-to-nearest-even fp32 -> bf16
__device__ __forceinline__ ushort f2bf(float f) {
    uint u = __float_as_uint(f);
    u += 0x7fffu + ((u >> 16) & 1u);
    return (ushort)(u >> 16);
}

// ---------------------------------------------------------------------------
// K0 (fused prep): W_cls pack + rs zero + out bias-init. All independent of the
// main chain; one launch instead of three.
//   blocks [0,42):          wcpack
//   blocks [42,42+3456):    rs = 0           (3456*256 == 884736 exactly)
//   blocks [3498,3935):     out[i] = bc[i%NCLS]
__global__ void k_prep(const float* __restrict__ Wc, ushort* __restrict__ wcpack,
                       float* __restrict__ rs, float* __restrict__ out,
                       const float* __restrict__ bc) {
    int bid = blockIdx.x;
    if (bid < 42) {
        int t = bid * 256 + threadIdx.x;
        if (t >= 24 * NCT * 64) return;
        int kc = t / (NCT * 64);
        int r = t % (NCT * 64);
        int ct = r >> 6;
        int lane = r & 63;
        int c = ct * 16 + (lane & 15);
        int k0 = kc * 32 + (lane >> 4) * 8;
        uint u[4] = {0u, 0u, 0u, 0u};
        if (c < NCLS) {
            const float* src = Wc + (size_t)c * HH + k0;
            float4 f0 = *(const float4*)src;
            float4 f1 = *(const float4*)(src + 4);
            u[0] = (uint)f2bf(f0.x) | ((uint)f2bf(f0.y) << 16);
            u[1] = (uint)f2bf(f0.z) | ((uint)f2bf(f0.w) << 16);
            u[2] = (uint)f2bf(f1.x) | ((uint)f2bf(f1.y) << 16);
            u[3] = (uint)f2bf(f1.z) | ((uint)f2bf(f1.w) << 16);
        }
        *(uint4*)(wcpack + (size_t)t * 8) = make_uint4(u[0], u[1], u[2], u[3]);
    } else if (bid < 42 + 3456) {
        int i = (bid - 42) * 256 + threadIdx.x;
        rs[i] = 0.f;
    } else {
        int i = (bid - 3498) * 256 + threadIdx.x;
        if (i < NEF * NCLS) out[i] = bc[i % NCLS];
    }
}

// K1 (fused head): per (b,e) block computes e_att (12x1024, kept in LDS +
// written to global for k_ht), gate (LDS only), and e_emb. Was 3 kernels.
// 48 blocks x 1024 threads.
__global__ void k_head(const float* __restrict__ att_in, const float* __restrict__ seq,
                       const int* __restrict__ ms, const int* __restrict__ cs,
                       float* __restrict__ e_att, float* __restrict__ e_emb) {
    __shared__ float es[NHH][LL];
    __shared__ float gs[LL];
    __shared__ float red[16];
    int be = blockIdx.x;
    int b = be / NEE;
    int base = be * MMM;
    int p0 = ms[base + 0] + 1;
    int p1 = ms[base + 1] + 1;
    int p2 = ms[base + 2] + 1;
    int l = threadIdx.x;                 // 0..1023
    // phase 1: e_att
    float* eo = e_att + (size_t)be * NHH * LL;
#pragma unroll
    for (int h = 0; h < NHH; h++) {
        const float* basep = att_in + (size_t)(b * NHH + h) * LL * LL;
        float v = (basep[(size_t)p0 * LL + l] + basep[(size_t)p1 * LL + l] +
                   basep[(size_t)p2 * LL + l]) * (1.f / 3.f);
        es[h][l] = v;
        eo[h * LL + l] = v;
    }
    __syncthreads();
    // phase 2: gate (LDS only)
    float a = 0.f;
#pragma unroll
    for (int h = 0; h < NHH; h++) a += es[h][l];
    float s = a;
    for (int off = 32; off; off >>= 1) s += __shfl_down(s, off, 64);
    if ((l & 63) == 0) red[l >> 6] = s;
    __syncthreads();
    float tot = 0.f;
#pragma unroll
    for (int i = 0; i < 16; i++) tot += red[i];
    gs[l] = a * (1.f / tot);
    __syncthreads();
    // phase 3: e_emb (768 threads active)
    if (l < HH) {
        int d = l;
        int c0 = cs[be * NCC + 0], c1 = cs[be * NCC + 1];
        float v0 = seq[((size_t)b * LL + p0) * HH + d];
        float v1 = seq[((size_t)b * LL + p1) * HH + d];
        float v2 = seq[((size_t)b * LL + p2) * HH + d];
        float s0 = 0.f, s1 = 0.f;
#pragma unroll
        for (int w = 0; w < CWW; w++) {
            s0 += gs[c0 + w] * seq[((size_t)b * LL + c0 + w) * HH + d];
            s1 += gs[c1 + w] * seq[((size_t)b * LL + c1 + w) * HH + d];
        }
        float mx = fmaxf(fmaxf(fmaxf(v0, v1), fmaxf(v2, s0)), s1);
        float se = expf(v0 - mx) + expf(v1 - mx) + expf(v2 - mx) + expf(s0 - mx) + expf(s1 - mx);
        e_emb[(size_t)be * HH + d] = logf(se) + mx;
    }
}

// K4: ht[b,e,f,l] = relu(sum_h e_att[b,e,h,l]*e_att[b,f,h,l]) normalized over l
__global__ void k_ht(const float* __restrict__ e_att, float* __restrict__ ht) {
    int blk = blockIdx.x;   // ((b*NEE+e)*NEE+f)
    int f = blk % NEE;
    int e = (blk / NEE) % NEE;
    int b = blk / (NEE * NEE);
    const float* ea = e_att + (size_t)(b * NEE + e) * NHH * LL;
    const float* fa = e_att + (size_t)(b * NEE + f) * NHH * LL;
    __shared__ float hts[LL];
    __shared__ float red[4];
    float lsum = 0.f;
    for (int l = threadIdx.x; l < LL; l += blockDim.x) {
        float s = 0.f;
        for (int h = 0; h < NHH; h++) s += ea[h * LL + l] * fa[h * LL + l];
        s = fmaxf(s, 0.f);
        hts[l] = s;
        lsum += s;
    }
    for (int off = 32; off; off >>= 1) lsum += __shfl_down(lsum, off, 64);
    if ((threadIdx.x & 63) == 0) red[threadIdx.x >> 6] = lsum;
    __syncthreads();
    float inv = 1.f / (red[0] + red[1] + red[2] + red[3] + 1e-10f);
    for (int l = threadIdx.x; l < LL; l += blockDim.x)
        ht[(size_t)blk * LL + l] = hts[l] * inv;
}

// K5 (fused mid): blocks [0,432) do the rs GEMM (64x64 tile, K split in two
// 512-halves, fp32 atomicAdd into zeroed rs); blocks [432,1584) do hsW/tsW.
// The two jobs are independent; fusing fills the machine and saves a launch.
__global__ void k_mid(const float* __restrict__ seq, const float* __restrict__ ht,
                      float* __restrict__ rs, const float* __restrict__ e_emb,
                      const float* __restrict__ Wh, const float* __restrict__ Wt,
                      float* __restrict__ hsW, float* __restrict__ tsW) {
    __shared__ float As[16][68], Bs[16][68];
    __shared__ float xs[HH];
    int bid = blockIdx.x;
    if (bid < 432) {
        int m0 = (bid % 9) * 64;
        int n0 = ((bid / 9) % 12) * 64;
        int z  = bid / 108;               // 0..3
        int b  = z >> 1;
        int k0base = (z & 1) * 512;
        const float* A  = ht  + (size_t)b * 576 * 1024;
        const float* Bm = seq + (size_t)b * 1024 * 768;
        float* C = rs + (size_t)b * 576 * 768;
        int tx = threadIdx.x & 15, ty = threadIdx.x >> 4;
        int lr = threadIdx.x >> 2;
        int lk = (threadIdx.x & 3) * 4;
        int kr = threadIdx.x >> 4;
        int c4 = (threadIdx.x & 15) * 4;
        float acc[4][4] = {};
        const float* arow = A + (size_t)(m0 + lr) * 1024 + k0base;
        const float* brow = Bm + (size_t)(k0base + kr) * 768 + n0 + c4;
        for (int k0 = 0; k0 < 512; k0 += 16) {
            float4 av = *(const float4*)(arow + k0 + lk);
            float4 bv = *(const float4*)(brow + (size_t)k0 * 768);
            __syncthreads();
            As[lk + 0][lr] = av.x; As[lk + 1][lr] = av.y; As[lk + 2][lr] = av.z; As[lk + 3][lr] = av.w;
            *(float4*)&Bs[kr][c4] = bv;
            __syncthreads();
#pragma unroll
            for (int kk = 0; kk < 16; kk++) {
                float a0 = As[kk][ty * 4 + 0], a1 = As[kk][ty * 4 + 1];
                float a2 = As[kk][ty * 4 + 2], a3 = As[kk][ty * 4 + 3];
                float b0 = Bs[kk][tx * 4 + 0], b1 = Bs[kk][tx * 4 + 1];
                float b2 = Bs[kk][tx * 4 + 2], b3 = Bs[kk][tx * 4 + 3];
                acc[0][0] += a0 * b0; acc[0][1] += a0 * b1; acc[0][2] += a0 * b2; acc[0][3] += a0 * b3;
                acc[1][0] += a1 * b0; acc[1][1] += a1 * b1; acc[1][2] += a1 * b2; acc[1][3] += a1 * b3;
                acc[2][0] += a2 * b0; acc[2][1] += a2 * b1; acc[2][2] += a2 * b2; acc[2][3] += a2 * b3;
                acc[3][0] += a3 * b0; acc[3][1] += a3 * b1; acc[3][2] += a3 * b2; acc[3][3] += a3 * b3;
            }
        }
#pragma unroll
        for (int i = 0; i < 4; i++)
#pragma unroll
            for (int j = 0; j < 4; j++)
                atomicAdd(&C[(size_t)(m0 + ty * 4 + i) * 768 + n0 + tx * 4 + j], acc[i][j]);
    } else {
        int r = bid - 432;                // 0..1151
        int m2 = r % 48;
        int which = (r / 48) & 1;
        int chunk = r / 96;               // 0..11
        const float* Wm = which ? Wt : Wh;
        float* outp = which ? tsW : hsW;
        const float* x = e_emb + (size_t)m2 * HH;
        for (int j = threadIdx.x; j < HH; j += 256) xs[j] = x[j];
        __syncthreads();
        int lane = threadIdx.x & 63, w = threadIdx.x >> 6;
        int d0 = chunk * 64 + w * 16;
#pragma unroll 4
        for (int i = 0; i < 16; i++) {
            int d = d0 + i;
            const float* wr = Wm + (size_t)d * (2 * HH);
            float s = 0.f;
#pragma unroll
            for (int jj = 0; jj < 12; jj++) s += xs[lane + jj * 64] * wr[lane + jj * 64];
            for (int off = 32; off; off >>= 1) s += __shfl_down(s, off, 64);
            if (lane == 0) outp[(size_t)m2 * HH + d] = s;
        }
    }
}

// K6 (rsW GEMM + fused tanh epilogue): zb[m,n] = bf16(tanh(rs@W2 + hs/ts + bias)).
// Same GEMM core as before; epilogue replaces the separate k_tanh launch and
// the rsW global round-trip.
__global__ void k_rsw(const float* __restrict__ rs, const float* __restrict__ Wh,
                      const float* __restrict__ Wt, const float* __restrict__ hsW,
                      const float* __restrict__ tsW, const float* __restrict__ bh,
                      const float* __restrict__ bt, ushort* __restrict__ zb) {
    int m0 = blockIdx.x * 64, n0 = blockIdx.y * 64;
    __shared__ float As[16][68], Bs[16][68];
    int tx = threadIdx.x & 15, ty = threadIdx.x >> 4;
    int lr = threadIdx.x >> 2;          // 0..63
    int lk = (threadIdx.x & 3) * 4;     // 0,4,8,12
    float acc[4][4] = {};
    int n = n0 + lr;
    const float* brow = (n < HH) ? (Wh + (size_t)n * (2 * HH) + HH)
                                 : (Wt + (size_t)(n - HH) * (2 * HH) + HH);
    const float* arow = rs + (size_t)(m0 + lr) * HH;
    for (int k0 = 0; k0 < HH; k0 += 16) {
        float4 av = *(const float4*)(arow + k0 + lk);
        float4 bv = *(const float4*)(brow + k0 + lk);
        __syncthreads();
        As[lk + 0][lr] = av.x; As[lk + 1][lr] = av.y; As[lk + 2][lr] = av.z; As[lk + 3][lr] = av.w;
        Bs[lk + 0][lr] = bv.x; Bs[lk + 1][lr] = bv.y; Bs[lk + 2][lr] = bv.z; Bs[lk + 3][lr] = bv.w;
        __syncthreads();
#pragma unroll
        for (int kk = 0; kk < 16; kk++) {
            float a0 = As[kk][ty * 4 + 0], a1 = As[kk][ty * 4 + 1];
            float a2 = As[kk][ty * 4 + 2], a3 = As[kk][ty * 4 + 3];
            float b0 = Bs[kk][tx * 4 + 0], b1 = Bs[kk][tx * 4 + 1];
            float b2 = Bs[kk][tx * 4 + 2], b3 = Bs[kk][tx * 4 + 3];
            acc[0][0] += a0 * b0; acc[0][1] += a0 * b1; acc[0][2] += a0 * b2; acc[0][3] += a0 * b3;
            acc[1][0] += a1 * b0; acc[1][1] += a1 * b1; acc[1][2] += a1 * b2; acc[1][3] += a1 * b3;
            acc[2][0] += a2 * b0; acc[2][1] += a2 * b1; acc[2][2] += a2 * b2; acc[2][3] += a2 * b3;
            acc[3][0] += a3 * b0; acc[3][1] += a3 * b1; acc[3][2] += a3 * b2; acc[3][3] += a3 * b3;
        }
    }
    bool isHead = (n0 < HH);            // n-tile is uniform: 768 % 64 == 0
#pragma unroll
    for (int i = 0; i < 4; i++) {
        int m = m0 + ty * 4 + i;
        int bb = m / 576;
        int rr = m % 576;
        int e = rr / NEE, f = rr % NEE;
        const float* addrow = isHead ? (hsW + (size_t)(bb * NEE + e) * HH)
                                     : (tsW + (size_t)(bb * NEE + f) * HH);
        const float* bias = isHead ? bh : bt;
#pragma unroll
        for (int j = 0; j < 4; j++) {
            int nn = n0 + tx * 4 + j;
            int d = isHead ? nn : (nn - HH);
            float v = tanhf(acc[i][j] + addrow[d] + bias[d]);
            zb[(size_t)m * (2 * HH) + nn] = f2bf(v);
        }
    }
}

// K8: bf16 MFMA GEMM for Wf: D[n, c] = sum_k Wp[k*HB + n] * Wc[c*HH + k].
// Barrier-free: A-fragments direct from global, B-fragments from L2-resident
// wcpack. Streams W_proj exactly once (147 MB -> ~23 us HBM floor).
__global__ void k_wf(const float* __restrict__ Wp, const ushort* __restrict__ wcpack,
                     ushort* __restrict__ bpack) {
    int tid = threadIdx.x;
    int lane = tid & 63, w = tid >> 6;
    int r16 = lane & 15, tt = lane >> 4;
    int n0 = blockIdx.x * 64 + w * 16;        // this wave's 16-n tile
    const float* ap = Wp + (size_t)(tt * 8) * HB + n0 + r16;
    const uint4* wb = (const uint4*)wcpack;

    f32x4 acc[NCT];
    f32x4 zero = {0.f, 0.f, 0.f, 0.f};
#pragma unroll
    for (int ct = 0; ct < NCT; ct++) acc[ct] = zero;

    for (int kc = 0; kc < 24; kc++) {
        const float* a0 = ap + (size_t)(kc * 32) * HB;
        float f[8];
#pragma unroll
        for (int j = 0; j < 8; j++) f[j] = a0[(size_t)j * HB];
        union { bf16x8 v; uint u[4]; } a;
#pragma unroll
        for (int q = 0; q < 4; q++)
            a.u[q] = (__float_as_uint(f[2 * q]) >> 16) |
                     (__float_as_uint(f[2 * q + 1]) & 0xFFFF0000u);  // truncate pair
#pragma unroll
        for (int ct = 0; ct < NCT; ct++) {
            union { uint4 q; bf16x8 v; } b;
            b.q = wb[(size_t)(kc * NCT + ct) * 64 + lane];
            acc[ct] = __builtin_amdgcn_mfma_f32_16x16x32_bf16(a.v, b.v, acc[ct], 0, 0, 0);
        }
    }
#pragma unroll
    for (int ct = 0; ct < NCT; ct++) {
        int c = ct * 16 + r16;
#pragma unroll
        for (int r = 0; r < 4; r++) {
            int n = n0 + tt * 4 + r;
            bpack[((size_t)(n >> 3) * NCP + c) * 8 + (n & 7)] = f2bf(acc[ct][r]);
        }
    }
}

// K9: MFMA logits. out[m,c] += sum over K-slice of bl[m,k]*Wf[c,k],
// bl generated on the fly in A-fragment layout from zh/zt LDS tiles.
#define ZTP 88
#define ZHP 48
__global__ __launch_bounds__(256, 2) void k_logits(const ushort* __restrict__ zb,
                                                   const ushort* __restrict__ bpack,
                                                   float* __restrict__ out) {
    __shared__ ushort zhs[64 * ZHP];
    __shared__ ushort zts[64 * ZTP];
    __shared__ ushort Bls[16384];   // 32 KB: one K=128 stage of B-fragments
    int m0 = blockIdx.x * 64;
    int kb = blockIdx.y;            // K-slice of 2048
    int kg = kb >> 1;               // which 4096-block (i*64+j space)
    int ihalf = (kb & 1) * 32;      // which half of the i range
    int tid = threadIdx.x;
    int lane = tid & 63, w = tid >> 6;
    int tt = lane >> 4, r16 = lane & 15;
    int wm = (w & 1) * 32, wn = (w >> 1) * 64;

    {
        int row = tid >> 2, c8 = (tid & 3) * 16;
        const ushort* src = zb + (size_t)(m0 + row) * 1536 + 768 + kg * 64 + c8;
        uint4 v0 = *(const uint4*)src;
        uint4 v1 = *(const uint4*)(src + 8);
        *(uint4*)&zts[row * ZTP + c8] = v0;
        *(uint4*)&zts[row * ZTP + c8 + 8] = v1;
    }
    {
        int row = tid >> 2, c8 = (tid & 3) * 8;
        const ushort* src = zb + (size_t)(m0 + row) * 1536 + kg * 64 + ihalf + c8;
        *(uint4*)&zhs[row * ZHP + c8] = *(const uint4*)src;
    }

    f32x4 acc[2][4];
    f32x4 zero = {0.f, 0.f, 0.f, 0.f};
#pragma unroll
    for (int t = 0; t < 2; t++)
#pragma unroll
        for (int n = 0; n < 4; n++) acc[t][n] = zero;

    const char* bbase = (const char*)bpack + (size_t)kb * 2048 * 256;
    for (int g = 0; g < 16; g++) {
        __syncthreads();
        const char* sb = bbase + (size_t)g * 32768;
#pragma unroll
        for (int q = 0; q < 8; q++) {
            int off = (q * 4 + w) * 1024;
            __builtin_amdgcn_global_load_lds(
                (const __attribute__((address_space(1))) void*)(sb + off + lane * 16),
                (__attribute__((address_space(3))) void*)((char*)Bls + off),
                16, 0, 0);
        }
        __syncthreads();
#pragma unroll
        for (int ks = 0; ks < 4; ks++) {
            int s = g * 4 + ks;
            int il = s >> 1;            // i within this slice's half
            int j0 = (s & 1) * 32;      // j chunk base
            bf16x8 af[2];
#pragma unroll
            for (int t = 0; t < 2; t++) {
                int row = wm + t * 16 + r16;
                float zhf = __uint_as_float((uint)zhs[row * ZHP + il] << 16);
                union { bf16x8 v; uint u[4]; } zt8, a;
                zt8.v = *(const bf16x8*)&zts[row * ZTP + j0 + tt * 8];
#pragma unroll
                for (int q = 0; q < 4; q++) {
                    uint p = zt8.u[q];
                    uint lo = __float_as_uint(__uint_as_float(p << 16) * zhf);
                    uint hi = __float_as_uint(__uint_as_float(p & 0xFFFF0000u) * zhf);
                    a.u[q] = (lo >> 16) | (hi & 0xFFFF0000u);   // truncate-to-bf16 pair
                }
                af[t] = a.v;
            }
#pragma unroll
            for (int n = 0; n < 4; n++) {
                bf16x8 bf = *(const bf16x8*)&Bls[(size_t)((ks * 4 + tt) * NCP + wn + n * 16 + r16) * 8];
                acc[0][n] = __builtin_amdgcn_mfma_f32_16x16x32_bf16(af[0], bf, acc[0][n], 0, 0, 0);
                acc[1][n] = __builtin_amdgcn_mfma_f32_16x16x32_bf16(af[1], bf, acc[1][n], 0, 0, 0);
            }
        }
    }
    int rbase = (lane >> 4) * 4;
#pragma unroll
    for (int t = 0; t < 2; t++)
#pragma unroll
        for (int n = 0; n < 4; n++) {
            int c = wn + n * 16 + r16;
            if (c < NCLS) {
                int row = m0 + wm + t * 16 + rbase;
#pragma unroll
                for (int r = 0; r < 4; r++)
                    atomicAdd(&out[(size_t)(row + r) * NCLS + c], acc[t][n][r]);
            }
        }
}

// ---------------------------------------------------------------------------
extern "C" void kernel_launch(void* const* d_in, const int* in_sizes, int n_in,
                              void* d_out, int out_size, void* d_ws, size_t ws_size,
                              hipStream_t stream) {
    const float* seq  = (const float*)d_in[0];
    const float* attn = (const float*)d_in[1];
    const int*   ms   = (const int*)d_in[2];
    const int*   cs   = (const int*)d_in[3];
    const float* Wh   = (const float*)d_in[4];
    const float* bh   = (const float*)d_in[5];
    const float* Wt   = (const float*)d_in[6];
    const float* bt   = (const float*)d_in[7];
    const float* Wp   = (const float*)d_in[8];
    const float* Wc   = (const float*)d_in[9];
    const float* bc   = (const float*)d_in[10];
    float* out = (float*)d_out;

    // Workspace layout (floats). The fp32 scratch region [0, 2764032) dies
    // after k_rsw; bpack (bf16 Wf, 12.58 MB) overlays it, written by k_wf.
    // zb and wcpack sit past bpack's end. Peak usage 16.3 MB (< 23.4 MB that
    // the previous layout proved available).
    float* w     = (float*)d_ws;
    float* e_att = w;                        //   589,824
    float* ht    = e_att + 589824;           // 1,179,648
    float* rs    = ht + 1179648;             //   884,736
    float* eemb  = rs + 884736;              //    36,864
    float* hsW   = eemb + 36864;             //    36,864
    float* tsW   = hsW + 36864;              //    36,864   (scratch ends 2,764,032)
    ushort* bpack  = (ushort*)w;               // 6,291,456 bf16 = floats [0, 3,145,728)
    ushort* zb     = (ushort*)(w + 3145728);   // 1,769,472 bf16
    ushort* wcpack = (ushort*)(w + 4030464);   //    86,016 bf16

    k_prep<<<3935, 256, 0, stream>>>(Wc, wcpack, rs, out, bc);
    k_head<<<BB * NEE, 1024, 0, stream>>>(attn, seq, ms, cs, e_att, eemb);
    k_ht<<<NEF, 256, 0, stream>>>(e_att, ht);
    k_mid<<<432 + 1152, 256, 0, stream>>>(seq, ht, rs, eemb, Wh, Wt, hsW, tsW);
    k_rsw<<<dim3(NEF / 64, 2 * HH / 64), 256, 0, stream>>>(rs, Wh, Wt, hsW, tsW, bh, bt, zb);
    k_wf<<<HB / 64, 256, 0, stream>>>(Wp, wcpack, bpack);   // clobbers fp32 scratch
    k_logits<<<dim3(NEF / 64, 24), 256, 0, stream>>>(zb, bpack, out);
}

// Round 3
// 447.821 us; speedup vs baseline: 1.5152x; 1.0304x over previous
//
#include <hip/hip_runtime.h>
#include <math.h>

// Problem constants
#define BB   2
#define LL   1024
#define HH   768
#define NHH  12
#define NEE  24
#define MMM  3
#define NCC  2
#define CWW  8
#define BLK  64
#define NCLS 97
#define HB   49152       // HH*BLK
#define NCP  128         // padded class dim for Wf
#define NCT  7           // class tiles computed (112 >= 97)
#define NEF  1152        // BB*NEE*NEE

typedef unsigned int uint;
typedef unsigned short ushort;
typedef __attribute__((ext_vector_type(8))) short bf16x8;
typedef __attribute__((ext_vector_type(4))) float f32x4;

// round-to-nearest-even fp32 -> bf16
__device__ __forceinline__ ushort f2bf(float f) {
    uint u = __float_as_uint(f);
    u += 0x7fffu + ((u >> 16) & 1u);
    return (ushort)(u >> 16);
}

// split fp32 into hi+lo bf16 (hi RNE, lo = RNE(f - hi)): ~16-bit mantissa total
__device__ __forceinline__ void splitbf(float f, ushort& h, ushort& l) {
    h = f2bf(f);
    float hf = __uint_as_float((uint)h << 16);
    l = f2bf(f - hf);
}

// ---------------------------------------------------------------------------
// K0 k_front: all input-only preprocessing in one launch.
//   [0,42):      wcpack (W_cls -> bf16 B-fragments)
//   [42,479):    out init with b_cls
//   [479,527):   head: e_att + gate + e_emb per (b,e)      (53KB LDS)
//   [527,911):   seq^T split-transpose -> seqThi/seqTlo [b][d][l]
//   [911,1295):  W2 split pack -> W2hi/W2lo [n][k] (cols 768: of Wh/Wt)
__global__ void k_front(const float* __restrict__ att_in, const float* __restrict__ seq,
                        const int* __restrict__ ms, const int* __restrict__ cs,
                        const float* __restrict__ Wc, const float* __restrict__ Wh,
                        const float* __restrict__ Wt, const float* __restrict__ bc,
                        float* __restrict__ e_att, float* __restrict__ e_emb,
                        ushort* __restrict__ wcpack,
                        ushort* __restrict__ seqThi, ushort* __restrict__ seqTlo,
                        ushort* __restrict__ W2hi, ushort* __restrict__ W2lo,
                        float* __restrict__ out) {
    __shared__ float sm[13328];     // head: es[12*1024]+gs[1024]+red[16]; transpose: 64x65
    int bid = blockIdx.x;
    int tid = threadIdx.x;
    if (bid < 42) {
        int t = bid * 256 + tid;
        if (t >= 24 * NCT * 64) return;
        int kc = t / (NCT * 64);
        int r = t % (NCT * 64);
        int ct = r >> 6;
        int lane = r & 63;
        int c = ct * 16 + (lane & 15);
        int k0 = kc * 32 + (lane >> 4) * 8;
        uint u[4] = {0u, 0u, 0u, 0u};
        if (c < NCLS) {
            const float* src = Wc + (size_t)c * HH + k0;
            float4 f0 = *(const float4*)src;
            float4 f1 = *(const float4*)(src + 4);
            u[0] = (uint)f2bf(f0.x) | ((uint)f2bf(f0.y) << 16);
            u[1] = (uint)f2bf(f0.z) | ((uint)f2bf(f0.w) << 16);
            u[2] = (uint)f2bf(f1.x) | ((uint)f2bf(f1.y) << 16);
            u[3] = (uint)f2bf(f1.z) | ((uint)f2bf(f1.w) << 16);
        }
        *(uint4*)(wcpack + (size_t)t * 8) = make_uint4(u[0], u[1], u[2], u[3]);
    } else if (bid < 479) {
        int i = (bid - 42) * 256 + tid;
        if (i < NEF * NCLS) out[i] = bc[i % NCLS];
    } else if (bid < 527) {
        // head: per (b,e)
        float* es = sm;                // 12*1024
        float* gs = sm + 12288;        // 1024
        float* red = sm + 13312;       // 4
        int be = bid - 479;
        int b = be / NEE;
        int base = be * MMM;
        int p0 = ms[base + 0] + 1, p1 = ms[base + 1] + 1, p2 = ms[base + 2] + 1;
        float* eo = e_att + (size_t)be * NHH * LL;
        for (int h = 0; h < NHH; h++) {
            const float* basep = att_in + (size_t)(b * NHH + h) * LL * LL;
#pragma unroll
            for (int i = 0; i < 4; i++) {
                int l = tid + i * 256;
                float v = (basep[(size_t)p0 * LL + l] + basep[(size_t)p1 * LL + l] +
                           basep[(size_t)p2 * LL + l]) * (1.f / 3.f);
                es[h * LL + l] = v;
                eo[h * LL + l] = v;
            }
        }
        __syncthreads();
        float part = 0.f;
#pragma unroll
        for (int i = 0; i < 4; i++) {
            int l = tid + i * 256;
            float a = 0.f;
#pragma unroll
            for (int h = 0; h < NHH; h++) a += es[h * LL + l];
            gs[l] = a;
            part += a;
        }
        for (int off = 32; off; off >>= 1) part += __shfl_down(part, off, 64);
        if ((tid & 63) == 0) red[tid >> 6] = part;
        __syncthreads();
        float inv = 1.f / (red[0] + red[1] + red[2] + red[3]);
#pragma unroll
        for (int i = 0; i < 4; i++) gs[tid + i * 256] *= inv;
        __syncthreads();
        int c0 = cs[be * NCC + 0], c1 = cs[be * NCC + 1];
        for (int d = tid; d < HH; d += 256) {
            float v0 = seq[((size_t)b * LL + p0) * HH + d];
            float v1 = seq[((size_t)b * LL + p1) * HH + d];
            float v2 = seq[((size_t)b * LL + p2) * HH + d];
            float s0 = 0.f, s1 = 0.f;
#pragma unroll
            for (int w = 0; w < CWW; w++) {
                s0 += gs[c0 + w] * seq[((size_t)b * LL + c0 + w) * HH + d];
                s1 += gs[c1 + w] * seq[((size_t)b * LL + c1 + w) * HH + d];
            }
            float mx = fmaxf(fmaxf(fmaxf(v0, v1), fmaxf(v2, s0)), s1);
            float se = expf(v0 - mx) + expf(v1 - mx) + expf(v2 - mx) + expf(s0 - mx) + expf(s1 - mx);
            e_emb[(size_t)be * HH + d] = logf(se) + mx;
        }
    } else if (bid < 911) {
        // seq^T split-transpose: 64(l) x 64(d) tiles
        float (*tile)[65] = (float(*)[65])sm;
        int idx = bid - 527;
        int b = idx / 192;
        int rem = idx % 192;
        int l0 = (rem / 12) * 64;
        int d0 = (rem % 12) * 64;
        int dq = tid >> 6, dl = tid & 63;
#pragma unroll 4
        for (int r = 0; r < 16; r++) {
            int l_in = r * 4 + dq;
            tile[l_in][dl] = seq[((size_t)(b * LL + l0 + l_in)) * HH + d0 + dl];
        }
        __syncthreads();
#pragma unroll 4
        for (int r = 0; r < 16; r++) {
            int d_out = r * 4 + dq;
            float v = tile[dl][d_out];
            ushort h, l;
            splitbf(v, h, l);
            size_t o = ((size_t)(b * HH + d0 + d_out)) * LL + l0 + dl;
            seqThi[o] = h;
            seqTlo[o] = l;
        }
    } else {
        // W2 split pack: W2[n][k] = (n<768 ? Wh : Wt)[n%768][768+k]
        int idx = bid - 911;
#pragma unroll
        for (int rr = 0; rr < 4; rr++) {
            int n = idx * 4 + rr;
            const float* src = (n < HH) ? (Wh + (size_t)n * (2 * HH) + HH)
                                        : (Wt + (size_t)(n - HH) * (2 * HH) + HH);
            for (int k = tid; k < HH; k += 256) {
                ushort h, l;
                splitbf(src[k], h, l);
                W2hi[(size_t)n * HH + k] = h;
                W2lo[(size_t)n * HH + k] = l;
            }
        }
    }
}

// ---------------------------------------------------------------------------
// K1 k_htwf: co-scheduled independent jobs.
//   [0,768):     wf  — bf16 MFMA GEMM Wf[n,c] (streams W_proj once, HBM-bound)
//   [768,1920):  ht  — relu+normalize, emitted pre-split as hthi/htlo
__global__ void k_htwf(const float* __restrict__ e_att, const float* __restrict__ Wp,
                       const ushort* __restrict__ wcpack, ushort* __restrict__ hthi,
                       ushort* __restrict__ htlo, ushort* __restrict__ bpack) {
    __shared__ float hts[LL];
    __shared__ float red[4];
    int bid = blockIdx.x;
    int tid = threadIdx.x;
    int lane = tid & 63, w = tid >> 6;
    if (bid < 768) {
        int r16 = lane & 15, tt = lane >> 4;
        int n0 = bid * 64 + w * 16;
        const float* ap = Wp + (size_t)(tt * 8) * HB + n0 + r16;
        const uint4* wb = (const uint4*)wcpack;
        f32x4 acc[NCT];
        f32x4 zero = {0.f, 0.f, 0.f, 0.f};
#pragma unroll
        for (int ct = 0; ct < NCT; ct++) acc[ct] = zero;
        for (int kc = 0; kc < 24; kc++) {
            const float* a0 = ap + (size_t)(kc * 32) * HB;
            float f[8];
#pragma unroll
            for (int j = 0; j < 8; j++) f[j] = a0[(size_t)j * HB];
            union { bf16x8 v; uint u[4]; } a;
#pragma unroll
            for (int q = 0; q < 4; q++)
                a.u[q] = (__float_as_uint(f[2 * q]) >> 16) |
                         (__float_as_uint(f[2 * q + 1]) & 0xFFFF0000u);
#pragma unroll
            for (int ct = 0; ct < NCT; ct++) {
                union { uint4 q; bf16x8 v; } b;
                b.q = wb[(size_t)(kc * NCT + ct) * 64 + lane];
                acc[ct] = __builtin_amdgcn_mfma_f32_16x16x32_bf16(a.v, b.v, acc[ct], 0, 0, 0);
            }
        }
#pragma unroll
        for (int ct = 0; ct < NCT; ct++) {
            int c = ct * 16 + r16;
#pragma unroll
            for (int r = 0; r < 4; r++) {
                int n = n0 + tt * 4 + r;
                bpack[((size_t)(n >> 3) * NCP + c) * 8 + (n & 7)] = f2bf(acc[ct][r]);
            }
        }
    } else {
        int blk = bid - 768;            // ((b*NEE+e)*NEE+f)
        int f = blk % NEE;
        int e = (blk / NEE) % NEE;
        int b = blk / (NEE * NEE);
        const float* ea = e_att + (size_t)(b * NEE + e) * NHH * LL;
        const float* fa = e_att + (size_t)(b * NEE + f) * NHH * LL;
        float lsum = 0.f;
        for (int l = tid; l < LL; l += 256) {
            float s = 0.f;
            for (int h = 0; h < NHH; h++) s += ea[h * LL + l] * fa[h * LL + l];
            s = fmaxf(s, 0.f);
            hts[l] = s;
            lsum += s;
        }
        for (int off = 32; off; off >>= 1) lsum += __shfl_down(lsum, off, 64);
        if ((tid & 63) == 0) red[tid >> 6] = lsum;
        __syncthreads();
        float inv = 1.f / (red[0] + red[1] + red[2] + red[3] + 1e-10f);
        for (int l = tid; l < LL; l += 256) {
            ushort h, lo;
            splitbf(hts[l] * inv, h, lo);
            hthi[(size_t)blk * LL + l] = h;
            htlo[(size_t)blk * LL + l] = lo;
        }
    }
}

// ---------------------------------------------------------------------------
// K2 k_mid:
//   [0,216):     rs GEMM via split-bf16 MFMA: rs[m,d] = sum_l ht[m,l]*seq[l,d],
//                emitted pre-split as rshi/rslo. Per batch M=576,N=768,K=1024.
//   [216,1368):  hsW/tsW (e_emb @ first-768-cols of Wh/Wt)
__global__ void k_mid(const ushort* __restrict__ seqThi, const ushort* __restrict__ seqTlo,
                      const ushort* __restrict__ hthi, const ushort* __restrict__ htlo,
                      const float* __restrict__ e_emb, const float* __restrict__ Wh,
                      const float* __restrict__ Wt, ushort* __restrict__ rshi,
                      ushort* __restrict__ rslo, float* __restrict__ hsW,
                      float* __restrict__ tsW) {
    __shared__ float xs[HH];
    int bid = blockIdx.x;
    int tid = threadIdx.x;
    int lane = tid & 63, w = tid >> 6;
    if (bid < 216) {
        int b = bid / 108;
        int rem = bid % 108;
        int m0 = (rem / 12) * 64;
        int n0 = (rem % 12) * 64;
        int r16 = lane & 15, tt = lane >> 4;
        const ushort* Ah = hthi + (size_t)(b * 576 + m0 + w * 16 + r16) * LL;
        const ushort* Al = htlo + (size_t)(b * 576 + m0 + w * 16 + r16) * LL;
        const ushort* Bh0 = seqThi + (size_t)(b * HH + n0 + r16) * LL;
        const ushort* Bl0 = seqTlo + (size_t)(b * HH + n0 + r16) * LL;
        f32x4 acc[4];
        f32x4 zero = {0.f, 0.f, 0.f, 0.f};
#pragma unroll
        for (int nt = 0; nt < 4; nt++) acc[nt] = zero;
        for (int kc = 0; kc < 32; kc++) {
            int ko = kc * 32 + tt * 8;
            bf16x8 ah = *(const bf16x8*)(Ah + ko);
            bf16x8 al = *(const bf16x8*)(Al + ko);
#pragma unroll
            for (int nt = 0; nt < 4; nt++) {
                bf16x8 bh = *(const bf16x8*)(Bh0 + (size_t)nt * 16 * LL + ko);
                bf16x8 bl = *(const bf16x8*)(Bl0 + (size_t)nt * 16 * LL + ko);
                acc[nt] = __builtin_amdgcn_mfma_f32_16x16x32_bf16(ah, bh, acc[nt], 0, 0, 0);
                acc[nt] = __builtin_amdgcn_mfma_f32_16x16x32_bf16(ah, bl, acc[nt], 0, 0, 0);
                acc[nt] = __builtin_amdgcn_mfma_f32_16x16x32_bf16(al, bh, acc[nt], 0, 0, 0);
            }
        }
#pragma unroll
        for (int nt = 0; nt < 4; nt++) {
#pragma unroll
            for (int r = 0; r < 4; r++) {
                int m = b * 576 + m0 + w * 16 + tt * 4 + r;
                int d = n0 + nt * 16 + r16;
                ushort h, l;
                splitbf(acc[nt][r], h, l);
                rshi[(size_t)m * HH + d] = h;
                rslo[(size_t)m * HH + d] = l;
            }
        }
    } else {
        int r = bid - 216;                // 0..1151
        int m2 = r % 48;
        int which = (r / 48) & 1;
        int chunk = r / 96;               // 0..11
        const float* Wm = which ? Wt : Wh;
        float* outp = which ? tsW : hsW;
        const float* x = e_emb + (size_t)m2 * HH;
        for (int j = tid; j < HH; j += 256) xs[j] = x[j];
        __syncthreads();
        int d0 = chunk * 64 + w * 16;
#pragma unroll 4
        for (int i = 0; i < 16; i++) {
            int d = d0 + i;
            const float* wr = Wm + (size_t)d * (2 * HH);
            float s = 0.f;
#pragma unroll
            for (int jj = 0; jj < 12; jj++) s += xs[lane + jj * 64] * wr[lane + jj * 64];
            for (int off = 32; off; off >>= 1) s += __shfl_down(s, off, 64);
            if (lane == 0) outp[(size_t)m2 * HH + d] = s;
        }
    }
}

// ---------------------------------------------------------------------------
// K3 k_rsw: split-bf16 MFMA GEMM + tanh epilogue -> zb.
// zb[m,n] = bf16(tanh(sum_k rs[m,k]*W2[n,k] + hs/ts + bias)). M=1152,N=1536,K=768.
__global__ void k_rsw(const ushort* __restrict__ rshi, const ushort* __restrict__ rslo,
                      const ushort* __restrict__ W2hi, const ushort* __restrict__ W2lo,
                      const float* __restrict__ hsW, const float* __restrict__ tsW,
                      const float* __restrict__ bh, const float* __restrict__ bt,
                      ushort* __restrict__ zb) {
    int m0 = blockIdx.x * 64, n0 = blockIdx.y * 64;
    int tid = threadIdx.x;
    int lane = tid & 63, w = tid >> 6;
    int r16 = lane & 15, tt = lane >> 4;
    const ushort* Ah = rshi + (size_t)(m0 + w * 16 + r16) * HH;
    const ushort* Al = rslo + (size_t)(m0 + w * 16 + r16) * HH;
    const ushort* Bh0 = W2hi + (size_t)(n0 + r16) * HH;
    const ushort* Bl0 = W2lo + (size_t)(n0 + r16) * HH;
    f32x4 acc[4];
    f32x4 zero = {0.f, 0.f, 0.f, 0.f};
#pragma unroll
    for (int nt = 0; nt < 4; nt++) acc[nt] = zero;
    for (int kc = 0; kc < 24; kc++) {
        int ko = kc * 32 + tt * 8;
        bf16x8 ah = *(const bf16x8*)(Ah + ko);
        bf16x8 al = *(const bf16x8*)(Al + ko);
#pragma unroll
        for (int nt = 0; nt < 4; nt++) {
            bf16x8 vbh = *(const bf16x8*)(Bh0 + (size_t)nt * 16 * HH + ko);
            bf16x8 vbl = *(const bf16x8*)(Bl0 + (size_t)nt * 16 * HH + ko);
            acc[nt] = __builtin_amdgcn_mfma_f32_16x16x32_bf16(ah, vbh, acc[nt], 0, 0, 0);
            acc[nt] = __builtin_amdgcn_mfma_f32_16x16x32_bf16(ah, vbl, acc[nt], 0, 0, 0);
            acc[nt] = __builtin_amdgcn_mfma_f32_16x16x32_bf16(al, vbh, acc[nt], 0, 0, 0);
        }
    }
    bool isHead = (n0 < HH);
    const float* bias = isHead ? bh : bt;
#pragma unroll
    for (int nt = 0; nt < 4; nt++) {
#pragma unroll
        for (int r = 0; r < 4; r++) {
            int m = m0 + w * 16 + tt * 4 + r;
            int n = n0 + nt * 16 + r16;
            int bb = m / 576;
            int rr = m % 576;
            int e = rr / NEE, f = rr % NEE;
            int d = isHead ? n : (n - HH);
            const float* addrow = isHead ? (hsW + (size_t)(bb * NEE + e) * HH)
                                         : (tsW + (size_t)(bb * NEE + f) * HH);
            float v = tanhf(acc[nt][r] + addrow[d] + bias[d]);
            zb[(size_t)m * (2 * HH) + n] = f2bf(v);
        }
    }
}

// ---------------------------------------------------------------------------
// K4 k_logits: MFMA logits (unchanged, verified). out[m,c] += bl[m,k]*Wf[c,k].
#define ZTP 88
#define ZHP 48
__global__ __launch_bounds__(256, 2) void k_logits(const ushort* __restrict__ zb,
                                                   const ushort* __restrict__ bpack,
                                                   float* __restrict__ out) {
    __shared__ ushort zhs[64 * ZHP];
    __shared__ ushort zts[64 * ZTP];
    __shared__ ushort Bls[16384];   // 32 KB: one K=128 stage of B-fragments
    int m0 = blockIdx.x * 64;
    int kb = blockIdx.y;            // K-slice of 2048
    int kg = kb >> 1;               // which 4096-block (i*64+j space)
    int ihalf = (kb & 1) * 32;      // which half of the i range
    int tid = threadIdx.x;
    int lane = tid & 63, w = tid >> 6;
    int tt = lane >> 4, r16 = lane & 15;
    int wm = (w & 1) * 32, wn = (w >> 1) * 64;

    {
        int row = tid >> 2, c8 = (tid & 3) * 16;
        const ushort* src = zb + (size_t)(m0 + row) * 1536 + 768 + kg * 64 + c8;
        uint4 v0 = *(const uint4*)src;
        uint4 v1 = *(const uint4*)(src + 8);
        *(uint4*)&zts[row * ZTP + c8] = v0;
        *(uint4*)&zts[row * ZTP + c8 + 8] = v1;
    }
    {
        int row = tid >> 2, c8 = (tid & 3) * 8;
        const ushort* src = zb + (size_t)(m0 + row) * 1536 + kg * 64 + ihalf + c8;
        *(uint4*)&zhs[row * ZHP + c8] = *(const uint4*)src;
    }

    f32x4 acc[2][4];
    f32x4 zero = {0.f, 0.f, 0.f, 0.f};
#pragma unroll
    for (int t = 0; t < 2; t++)
#pragma unroll
        for (int n = 0; n < 4; n++) acc[t][n] = zero;

    const char* bbase = (const char*)bpack + (size_t)kb * 2048 * 256;
    for (int g = 0; g < 16; g++) {
        __syncthreads();
        const char* sb = bbase + (size_t)g * 32768;
#pragma unroll
        for (int q = 0; q < 8; q++) {
            int off = (q * 4 + w) * 1024;
            __builtin_amdgcn_global_load_lds(
                (const __attribute__((address_space(1))) void*)(sb + off + lane * 16),
                (__attribute__((address_space(3))) void*)((char*)Bls + off),
                16, 0, 0);
        }
        __syncthreads();
#pragma unroll
        for (int ks = 0; ks < 4; ks++) {
            int s = g * 4 + ks;
            int il = s >> 1;            // i within this slice's half
            int j0 = (s & 1) * 32;      // j chunk base
            bf16x8 af[2];
#pragma unroll
            for (int t = 0; t < 2; t++) {
                int row = wm + t * 16 + r16;
                float zhf = __uint_as_float((uint)zhs[row * ZHP + il] << 16);
                union { bf16x8 v; uint u[4]; } zt8, a;
                zt8.v = *(const bf16x8*)&zts[row * ZTP + j0 + tt * 8];
#pragma unroll
                for (int q = 0; q < 4; q++) {
                    uint p = zt8.u[q];
                    uint lo = __float_as_uint(__uint_as_float(p << 16) * zhf);
                    uint hi = __float_as_uint(__uint_as_float(p & 0xFFFF0000u) * zhf);
                    a.u[q] = (lo >> 16) | (hi & 0xFFFF0000u);   // truncate-to-bf16 pair
                }
                af[t] = a.v;
            }
#pragma unroll
            for (int n = 0; n < 4; n++) {
                bf16x8 bf = *(const bf16x8*)&Bls[(size_t)((ks * 4 + tt) * NCP + wn + n * 16 + r16) * 8];
                acc[0][n] = __builtin_amdgcn_mfma_f32_16x16x32_bf16(af[0], bf, acc[0][n], 0, 0, 0);
                acc[1][n] = __builtin_amdgcn_mfma_f32_16x16x32_bf16(af[1], bf, acc[1][n], 0, 0, 0);
            }
        }
    }
    int rbase = (lane >> 4) * 4;
#pragma unroll
    for (int t = 0; t < 2; t++)
#pragma unroll
        for (int n = 0; n < 4; n++) {
            int c = wn + n * 16 + r16;
            if (c < NCLS) {
                int row = m0 + wm + t * 16 + rbase;
#pragma unroll
                for (int r = 0; r < 4; r++)
                    atomicAdd(&out[(size_t)(row + r) * NCLS + c], acc[t][n][r]);
            }
        }
}

// ---------------------------------------------------------------------------
extern "C" void kernel_launch(void* const* d_in, const int* in_sizes, int n_in,
                              void* d_out, int out_size, void* d_ws, size_t ws_size,
                              hipStream_t stream) {
    const float* seq  = (const float*)d_in[0];
    const float* attn = (const float*)d_in[1];
    const int*   ms   = (const int*)d_in[2];
    const int*   cs   = (const int*)d_in[3];
    const float* Wh   = (const float*)d_in[4];
    const float* bh   = (const float*)d_in[5];
    const float* Wt   = (const float*)d_in[6];
    const float* bt   = (const float*)d_in[7];
    const float* Wp   = (const float*)d_in[8];
    const float* Wc   = (const float*)d_in[9];
    const float* bc   = (const float*)d_in[10];
    float* out = (float*)d_out;

    // Workspace layout (no overlays; ~38 MB total, workspace is ~600 MB).
    float* w     = (float*)d_ws;
    float* e_att = w;                          //   589,824 f
    float* eemb  = e_att + 589824;             //    36,864 f
    float* hsW   = eemb + 36864;               //    36,864 f
    float* tsW   = hsW + 36864;                //    36,864 f
    ushort* seqThi = (ushort*)(tsW + 36864);   // 1,572,864 us  [b][d][l]
    ushort* seqTlo = seqThi + 1572864;         // 1,572,864 us
    ushort* W2hi   = seqTlo + 1572864;         // 1,179,648 us  [n][k]
    ushort* W2lo   = W2hi + 1179648;           // 1,179,648 us
    ushort* hthi   = W2lo + 1179648;           // 1,179,648 us  [m][l]
    ushort* htlo   = hthi + 1179648;           // 1,179,648 us
    ushort* rshi   = htlo + 1179648;           //   884,736 us  [m][d]
    ushort* rslo   = rshi + 884736;            //   884,736 us
    ushort* zb     = rslo + 884736;            // 1,769,472 us  [m][n]
    ushort* wcpack = zb + 1769472;             //    86,016 us
    ushort* bpack  = wcpack + 86016;           // 6,291,456 us

    k_front<<<1295, 256, 0, stream>>>(attn, seq, ms, cs, Wc, Wh, Wt, bc,
                                      e_att, eemb, wcpack, seqThi, seqTlo, W2hi, W2lo, out);
    k_htwf<<<1920, 256, 0, stream>>>(e_att, Wp, wcpack, hthi, htlo, bpack);
    k_mid<<<1368, 256, 0, stream>>>(seqThi, seqTlo, hthi, htlo, eemb, Wh, Wt,
                                    rshi, rslo, hsW, tsW);
    k_rsw<<<dim3(18, 24), 256, 0, stream>>>(rshi, rslo, W2hi, W2lo, hsW, tsW, bh, bt, zb);
    k_logits<<<dim3(18, 24), 256, 0, stream>>>(zb, bpack, out);
}